// Round 1
// baseline (153.184 us; speedup 1.0000x reference)
//
#include <hip/hip_runtime.h>

// Problem constants (fixed by the reference setup):
constexpr int Bv = 16, Hv = 768, Wv = 2048;
constexpr int ROWS_PER_BLOCK = 4;                 // Hv % 4 == 0 -> block stays in one image
constexpr int NROWS   = Bv * Hv;                  // 12288
constexpr int NBLOCKS = NROWS / ROWS_PER_BLOCK;   // 3072 (ws need: 3072*8 B = 24 KiB)
constexpr int MAXN    = 256;                      // max boxes per image we can stage

__global__ __launch_bounds__(256) void balancer_main(
    const float* __restrict__ loss,
    const float* __restrict__ boxes,
    const int*   __restrict__ num_gt,
    double*      __restrict__ partials)
{
    const int tid  = threadIdx.x;
    const int row0 = blockIdx.x * ROWS_PER_BLOCK;
    const int b    = row0 / Hv;                   // block-uniform image index
    const int n    = num_gt[0];

    __shared__ float s_y1[MAXN], s_y2[MAXN];
    __shared__ int   s_x1[MAXN], s_x2[MAXN];
    __shared__ int   s_u1[MAXN], s_u2[MAXN];      // compacted active intervals for current row
    __shared__ int   s_cnt;

    // Preload this image's boxes into LDS once per block.
    for (int i = tid; i < n && i < MAXN; i += blockDim.x) {
        const float* bx = boxes + (size_t)(b * n + i) * 4;
        s_x1[i] = (int)floorf(bx[0]);
        s_y1[i] = bx[1];
        s_x2[i] = (int)ceilf(bx[2]);
        s_y2[i] = bx[3];
    }

    float sum = 0.0f;

    for (int r = 0; r < ROWS_PER_BLOCK; ++r) {
        const int row = row0 + r;
        const int h   = row - b * Hv;

        __syncthreads();                          // covers preload (r=0) / prev row's reads
        if (tid == 0) s_cnt = 0;
        __syncthreads();

        // Compact boxes whose row-range contains h (E[m] ~ 4.3 of 32).
        for (int i = tid; i < n && i < MAXN; i += blockDim.x) {
            const int v1 = (int)floorf(s_y1[i]);
            const int v2 = (int)ceilf(s_y2[i]);
            if (h >= v1 && h < v2) {
                const int pos = atomicAdd(&s_cnt, 1);
                s_u1[pos] = s_x1[i];
                s_u2[pos] = s_x2[i];
            }
        }
        __syncthreads();
        const int m = s_cnt;                      // block-uniform -> no divergence

        // 2048 cols = 512 float4; 256 threads -> 2 coalesced float4 each.
        const float4* rowp = (const float4*)(loss + (size_t)row * Wv);
        #pragma unroll
        for (int it = 0; it < Wv / (256 * 4); ++it) {
            const int    idx4 = it * 256 + tid;
            const float4 v    = rowp[idx4];
            const int    c0   = idx4 * 4;
            bool f0 = false, f1 = false, f2 = false, f3 = false;
            for (int i = 0; i < m; ++i) {         // s_u1[i]/s_u2[i]: same-addr broadcast, conflict-free
                const int u1 = s_u1[i], u2 = s_u2[i];
                f0 |= (c0     >= u1) & (c0     < u2);
                f1 |= (c0 + 1 >= u1) & (c0 + 1 < u2);
                f2 |= (c0 + 2 >= u1) & (c0 + 2 < u2);
                f3 |= (c0 + 3 >= u1) & (c0 + 3 < u2);
            }
            sum += v.x * (f0 ? 13.0f : 1.0f);
            sum += v.y * (f1 ? 13.0f : 1.0f);
            sum += v.z * (f2 ? 13.0f : 1.0f);
            sum += v.w * (f3 ? 13.0f : 1.0f);
        }
    }

    // Wave-64 shuffle reduction (fp32 leaves, tiny magnitudes -> safe).
    for (int off = 32; off > 0; off >>= 1)
        sum += __shfl_down(sum, off, 64);

    __shared__ float s_wsum[4];
    const int lane = tid & 63;
    const int wid  = tid >> 6;
    if (lane == 0) s_wsum[wid] = sum;
    __syncthreads();
    if (tid == 0) {
        double d = 0.0;
        #pragma unroll
        for (int wq = 0; wq < 4; ++wq) d += (double)s_wsum[wq];
        partials[blockIdx.x] = d;                 // plain store: no atomics, deterministic
    }
}

__global__ __launch_bounds__(256) void balancer_reduce(
    const double* __restrict__ partials, float* __restrict__ out)
{
    const int tid = threadIdx.x;
    double s = 0.0;
    for (int i = tid; i < NBLOCKS; i += 256) s += partials[i];
    for (int off = 32; off > 0; off >>= 1)
        s += __shfl_down(s, off, 64);
    __shared__ double sh[4];
    if ((tid & 63) == 0) sh[tid >> 6] = s;
    __syncthreads();
    if (tid == 0) {
        const double t = sh[0] + sh[1] + sh[2] + sh[3];
        out[0] = (float)(t / (double)((long long)Bv * Hv * Wv));
    }
}

extern "C" void kernel_launch(void* const* d_in, const int* in_sizes, int n_in,
                              void* d_out, int out_size, void* d_ws, size_t ws_size,
                              hipStream_t stream) {
    const float* loss   = (const float*)d_in[0];
    const float* boxes  = (const float*)d_in[1];
    const int*   num_gt = (const int*)d_in[2];
    double*      partials = (double*)d_ws;        // 24 KiB needed
    float*       out      = (float*)d_out;

    balancer_main<<<NBLOCKS, 256, 0, stream>>>(loss, boxes, num_gt, partials);
    balancer_reduce<<<1, 256, 0, stream>>>(partials, out);
}